// Round 7
// baseline (532.245 us; speedup 1.0000x reference)
//
#include <hip/hip_runtime.h>
#include <hip/hip_bf16.h>

#define HID 128
#define NNODES 50000
#define NEDGES 800000
#define NGRAPHS 64
#define BN_EPS 1e-5f
#define SCAN_CHUNK 196  // 256*196 = 50176 >= 50000

typedef __attribute__((ext_vector_type(8))) short short8;   // 8 bf16 (4 VGPRs)
typedef __attribute__((ext_vector_type(4))) float f32x4;    // MFMA acc

static __device__ __forceinline__ unsigned short f2bf(float v) {
  __hip_bfloat16 b = __float2bfloat16(v);  // round-to-nearest
  return *reinterpret_cast<unsigned short*>(&b);
}
static __device__ __forceinline__ float bf2f(unsigned short u) {
  return __uint_as_float(((unsigned)u) << 16);
}

// split fp32 -> hi+lo bf16 pair (bf16x3 scheme), 8 contiguous LDS floats
static __device__ __forceinline__ void split8(const float* __restrict__ p,
                                              short8& hi, short8& lo) {
  #pragma unroll
  for (int j = 0; j < 8; j++) {
    float v = p[j];
    unsigned short h = f2bf(v);
    hi[j] = (short)h;
    lo[j] = (short)f2bf(v - bf2f(h));
  }
}

// ===========================================================================
// prep: x = node_emb[x_idx] (fp32, float4) + in-degree histogram
// ===========================================================================
__global__ __launch_bounds__(256) void prep_kernel(
    const int* __restrict__ x_idx, const float* __restrict__ node_emb,
    float* __restrict__ x, const int* __restrict__ eidx,
    int* __restrict__ deg) {
  int i = blockIdx.x * 256 + threadIdx.x;
  int stride = gridDim.x * 256;
  const float4* ne4 = (const float4*)node_emb;
  float4* x4 = (float4*)x;
  for (int t = i; t < NNODES * (HID / 4); t += stride) {
    int n = t >> 5;  // HID/4 == 32
    int c4 = t & 31;
    x4[t] = ne4[x_idx[n] * 32 + c4];
  }
  for (int t = i; t < NEDGES; t += stride)
    atomicAdd(&deg[eidx[NEDGES + t]], 1);
}

// ===========================================================================
// Weight pre-pack into MFMA B-fragment layout, split hi/lo bf16.
// Frag (gemm m, ch-tile t, k-chunk q): lane l holds W[k=(l>>4)*8+j+q*32][n=t*16+(l&15)]
// hi at idx, lo at idx + 65536; idx = (((m*8+t)*4+q)*64+l)*8 + j
// ===========================================================================
__global__ __launch_bounds__(256) void wpack_kernel(
    const float* __restrict__ W1, const float* __restrict__ W2,
    unsigned short* __restrict__ Wpk) {
  int idx = blockIdx.x * 256 + threadIdx.x;  // 65536 total
  int j = idx & 7;
  int l = (idx >> 3) & 63;
  int q = (idx >> 9) & 3;
  int t = (idx >> 11) & 7;
  int m = idx >> 14;
  int k = ((l >> 4) << 3) + j + (q << 5);
  int n = (t << 4) + (l & 15);
  int layer = m >> 1;
  const float* W = (m & 1) ? W2 : W1;
  float w = W[(size_t)layer * HID * HID + k * HID + n];
  unsigned short h = f2bf(w);
  Wpk[idx] = h;
  Wpk[idx + 65536] = f2bf(w - bf2f(h));
}

// ===========================================================================
// CSR build (3-pass coalesced scan + scatter)
// ===========================================================================
__global__ __launch_bounds__(256) void chunksum_kernel(
    const int* __restrict__ deg, int* __restrict__ csum) {
  __shared__ int s[256];
  int b = blockIdx.x, t = threadIdx.x;
  int idx = b * SCAN_CHUNK + t;
  s[t] = (t < SCAN_CHUNK && idx < NNODES) ? deg[idx] : 0;
  __syncthreads();
  for (int off = 128; off > 0; off >>= 1) {
    if (t < off) s[t] += s[t + off];
    __syncthreads();
  }
  if (t == 0) csum[b] = s[0];
}

__global__ __launch_bounds__(256) void scanbase_kernel(
    const int* __restrict__ csum, int* __restrict__ cbase) {
  __shared__ int s[256];
  int t = threadIdx.x;
  int v = csum[t];
  s[t] = v;
  __syncthreads();
  for (int off = 1; off < 256; off <<= 1) {
    int u = (t >= off) ? s[t - off] : 0;
    __syncthreads();
    s[t] += u;
    __syncthreads();
  }
  cbase[t] = s[t] - v;  // exclusive
}

__global__ __launch_bounds__(256) void scan2_kernel(
    const int* __restrict__ deg, const int* __restrict__ cbase,
    int* __restrict__ offs, int* __restrict__ cursor) {
  __shared__ int s[256];
  int b = blockIdx.x, t = threadIdx.x;
  int idx = b * SCAN_CHUNK + t;
  int val = (t < SCAN_CHUNK && idx < NNODES) ? deg[idx] : 0;
  s[t] = val;
  __syncthreads();
  for (int off = 1; off < 256; off <<= 1) {
    int u = (t >= off) ? s[t - off] : 0;
    __syncthreads();
    s[t] += u;
    __syncthreads();
  }
  if (t < SCAN_CHUNK && idx < NNODES) {
    int excl = cbase[b] + s[t] - val;
    offs[idx] = excl;
    cursor[idx] = excl;
  }
  if (b == 0 && t == 0) offs[NNODES] = NEDGES;
}

__global__ __launch_bounds__(256) void scatter_kernel(
    const int* __restrict__ eidx, const int* __restrict__ eattr,
    int* __restrict__ cursor, int* __restrict__ eout) {
  int e = blockIdx.x * 256 + threadIdx.x;
  if (e >= NEDGES) return;
  int d = eidx[NEDGES + e];
  int pos = atomicAdd(&cursor[d], 1);
  eout[pos] = eidx[e] | (eattr[e] << 16);  // src<65536, attr<4
}

// ===========================================================================
// Fused GINE layer, bf16x3 MFMA MLP (fp32-grade accuracy).
// Block = 256 thr (4 waves), node tile NT=32.
// Phase 1 gather (thread=channel): h0 fp32 -> hA (fp32 LDS).
// Phase 2 GEMM1 mfma (split hi/lo in-register) -> hB fp32.
// Phase 3 GEMM2 -> hA reused as fp32 hC.
// Phase 4 epilogue: stats + (h2 write | run-length pool).
// ===========================================================================
#define NT 32
#define LDAF 132  // 128+4 floats: 16B-aligned rows, 4-bank rotation (2-way max)
#define GRID_GINE ((NNODES + NT - 1) / NT)  // 1563

__global__ __launch_bounds__(256, 4) void gine_mlp_kernel(
    const float* __restrict__ in, const float* __restrict__ instats,
    const float* __restrict__ gam, const float* __restrict__ bet,
    const int* __restrict__ offs, const int* __restrict__ eout,
    const float* __restrict__ edge_emb,
    const short8* __restrict__ Wh, const short8* __restrict__ Wl,
    const float* __restrict__ b1, const float* __restrict__ b2,
    float* __restrict__ out_f, float* __restrict__ stats,
    const int* __restrict__ batch, float* __restrict__ gpool) {
  __shared__ __align__(16) float hA[NT * LDAF];  // h0, later reused as hC
  __shared__ __align__(16) float hB[NT * LDAF];

  const int tid = threadIdx.x;
  const int lane = tid & 63;
  const int wave = tid >> 6;
  const int c = tid & 127;   // gather/epilogue channel
  const int yy = tid >> 7;   // 0/1 -> nodes [yy*16, yy*16+16)
  const int base = blockIdx.x * NT;

  // ---- per-channel affine (BN of previous layer folded) ----
  float scl = 1.0f, sh = 0.0f;
  if (instats) {
    float mu = instats[c] * (1.0f / NNODES);
    float var = instats[HID + c] * (1.0f / NNODES) - mu * mu;
    scl = gam[c] * rsqrtf(var + BN_EPS);
    sh = bet[c] - mu * scl;
  }
  float she0 = sh + edge_emb[0 * HID + c];
  float she1 = sh + edge_emb[1 * HID + c];
  float she2 = sh + edge_emb[2 * HID + c];
  float she3 = sh + edge_emb[3 * HID + c];

  // ---- phase 1: gather ----
  {
    int node0 = base + yy * 16;
    int eCur = offs[min(node0, NNODES)];
    for (int i = 0; i < 16; i++) {
      int n = yy * 16 + i;
      int node = node0 + i;
      if (node < NNODES) {
        int eEnd = offs[node + 1];
        float v = fmaf(in[node * HID + c], scl, sh);
        int e = eCur;
        for (; e + 8 <= eEnd; e += 8) {
          int p[8];
          float xs[8];
          #pragma unroll
          for (int u = 0; u < 8; u++) p[u] = eout[e + u];
          #pragma unroll
          for (int u = 0; u < 8; u++) xs[u] = in[(p[u] & 0xFFFF) * HID + c];
          #pragma unroll
          for (int u = 0; u < 8; u++) {
            int a = p[u] >> 16;
            float se = (a == 0) ? she0 : (a == 1) ? she1 : (a == 2) ? she2 : she3;
            v += fmaxf(fmaf(xs[u], scl, se), 0.0f);
          }
        }
        for (; e < eEnd; e++) {
          int p = eout[e];
          int a = p >> 16;
          float se = (a == 0) ? she0 : (a == 1) ? she1 : (a == 2) ? she2 : she3;
          v += fmaxf(fmaf(in[(p & 0xFFFF) * HID + c], scl, se), 0.0f);
        }
        hA[n * LDAF + c] = v;
        eCur = eEnd;
      } else {
        hA[n * LDAF + c] = 0.0f;
      }
    }
  }
  __syncthreads();

  const int col = lane & 15;
  const int quad = lane >> 4;
  const int rbase = quad * 4;
  const int ch0 = wave * 32 + col;
  const int ch1 = ch0 + 16;
  const int aoff = quad * 8;  // k-offset of this lane's A elements

  // ---- phase 2: GEMM1 (hA @ W1 + b1, relu) -> hB fp32 ----
  {
    f32x4 a00 = {0.f, 0.f, 0.f, 0.f}, a01 = a00, a10 = a00, a11 = a00;
    #pragma unroll
    for (int q = 0; q < 4; q++) {
      int f0 = (wave * 2 + 0) * 256 + q * 64 + lane;
      int f1 = (wave * 2 + 1) * 256 + q * 64 + lane;
      short8 b0h = Wh[f0], b0l = Wl[f0];
      short8 b1h = Wh[f1], b1l = Wl[f1];
      short8 a0h, a0l, a1h, a1l;
      split8(&hA[col * LDAF + q * 32 + aoff], a0h, a0l);
      split8(&hA[(16 + col) * LDAF + q * 32 + aoff], a1h, a1l);
      a00 = __builtin_amdgcn_mfma_f32_16x16x32_bf16(a0h, b0h, a00, 0, 0, 0);
      a00 = __builtin_amdgcn_mfma_f32_16x16x32_bf16(a0l, b0h, a00, 0, 0, 0);
      a00 = __builtin_amdgcn_mfma_f32_16x16x32_bf16(a0h, b0l, a00, 0, 0, 0);
      a01 = __builtin_amdgcn_mfma_f32_16x16x32_bf16(a0h, b1h, a01, 0, 0, 0);
      a01 = __builtin_amdgcn_mfma_f32_16x16x32_bf16(a0l, b1h, a01, 0, 0, 0);
      a01 = __builtin_amdgcn_mfma_f32_16x16x32_bf16(a0h, b1l, a01, 0, 0, 0);
      a10 = __builtin_amdgcn_mfma_f32_16x16x32_bf16(a1h, b0h, a10, 0, 0, 0);
      a10 = __builtin_amdgcn_mfma_f32_16x16x32_bf16(a1l, b0h, a10, 0, 0, 0);
      a10 = __builtin_amdgcn_mfma_f32_16x16x32_bf16(a1h, b0l, a10, 0, 0, 0);
      a11 = __builtin_amdgcn_mfma_f32_16x16x32_bf16(a1h, b1h, a11, 0, 0, 0);
      a11 = __builtin_amdgcn_mfma_f32_16x16x32_bf16(a1l, b1h, a11, 0, 0, 0);
      a11 = __builtin_amdgcn_mfma_f32_16x16x32_bf16(a1h, b1l, a11, 0, 0, 0);
    }
    float bb0 = b1[ch0], bb1 = b1[ch1];
    #pragma unroll
    for (int r = 0; r < 4; r++) {
      hB[(rbase + r) * LDAF + ch0] = fmaxf(a00[r] + bb0, 0.0f);
      hB[(rbase + r) * LDAF + ch1] = fmaxf(a01[r] + bb1, 0.0f);
      hB[(16 + rbase + r) * LDAF + ch0] = fmaxf(a10[r] + bb0, 0.0f);
      hB[(16 + rbase + r) * LDAF + ch1] = fmaxf(a11[r] + bb1, 0.0f);
    }
  }
  __syncthreads();  // hB ready; also: all GEMM1 reads of hA are done

  // ---- phase 3: GEMM2 (hB @ W2 + b2, relu) -> hC (reuse hA) ----
  {
    f32x4 a00 = {0.f, 0.f, 0.f, 0.f}, a01 = a00, a10 = a00, a11 = a00;
    #pragma unroll
    for (int q = 0; q < 4; q++) {
      int f0 = 2048 + (wave * 2 + 0) * 256 + q * 64 + lane;  // gemm2 frags
      int f1 = 2048 + (wave * 2 + 1) * 256 + q * 64 + lane;
      short8 b0h = Wh[f0], b0l = Wl[f0];
      short8 b1h = Wh[f1], b1l = Wl[f1];
      short8 a0h, a0l, a1h, a1l;
      split8(&hB[col * LDAF + q * 32 + aoff], a0h, a0l);
      split8(&hB[(16 + col) * LDAF + q * 32 + aoff], a1h, a1l);
      a00 = __builtin_amdgcn_mfma_f32_16x16x32_bf16(a0h, b0h, a00, 0, 0, 0);
      a00 = __builtin_amdgcn_mfma_f32_16x16x32_bf16(a0l, b0h, a00, 0, 0, 0);
      a00 = __builtin_amdgcn_mfma_f32_16x16x32_bf16(a0h, b0l, a00, 0, 0, 0);
      a01 = __builtin_amdgcn_mfma_f32_16x16x32_bf16(a0h, b1h, a01, 0, 0, 0);
      a01 = __builtin_amdgcn_mfma_f32_16x16x32_bf16(a0l, b1h, a01, 0, 0, 0);
      a01 = __builtin_amdgcn_mfma_f32_16x16x32_bf16(a0h, b1l, a01, 0, 0, 0);
      a10 = __builtin_amdgcn_mfma_f32_16x16x32_bf16(a1h, b0h, a10, 0, 0, 0);
      a10 = __builtin_amdgcn_mfma_f32_16x16x32_bf16(a1l, b0h, a10, 0, 0, 0);
      a10 = __builtin_amdgcn_mfma_f32_16x16x32_bf16(a1h, b0l, a10, 0, 0, 0);
      a11 = __builtin_amdgcn_mfma_f32_16x16x32_bf16(a1h, b1h, a11, 0, 0, 0);
      a11 = __builtin_amdgcn_mfma_f32_16x16x32_bf16(a1l, b1h, a11, 0, 0, 0);
      a11 = __builtin_amdgcn_mfma_f32_16x16x32_bf16(a1h, b1l, a11, 0, 0, 0);
    }
    float bb0 = b2[ch0], bb1 = b2[ch1];
    #pragma unroll
    for (int r = 0; r < 4; r++) {
      hA[(rbase + r) * LDAF + ch0] = fmaxf(a00[r] + bb0, 0.0f);
      hA[(rbase + r) * LDAF + ch1] = fmaxf(a01[r] + bb1, 0.0f);
      hA[(16 + rbase + r) * LDAF + ch0] = fmaxf(a10[r] + bb0, 0.0f);
      hA[(16 + rbase + r) * LDAF + ch1] = fmaxf(a11[r] + bb1, 0.0f);
    }
  }
  __syncthreads();

  // ---- phase 4: epilogue (hC == hA) ----
  float lsum = 0.0f, lsq = 0.0f;
  if (out_f) {
    #pragma unroll 4
    for (int i = 0; i < 16; i++) {
      int n = yy * 16 + i;
      int node = base + n;
      if (node < NNODES) {
        float v = hA[n * LDAF + c];
        out_f[node * HID + c] = v;
        lsum += v;
        lsq += v * v;
      }
    }
  } else {
    int curg = -1;
    float pacc = 0.0f;
    for (int i = 0; i < 16; i++) {
      int n = yy * 16 + i;
      int node = base + n;
      if (node < NNODES) {
        float v = hA[n * LDAF + c];
        lsum += v;
        lsq += v * v;
        int bg = batch[node];
        if (bg != curg) {
          if (curg >= 0) unsafeAtomicAdd(&gpool[curg * HID + c], pacc);
          curg = bg;
          pacc = 0.0f;
        }
        pacc += v;
      }
    }
    if (curg >= 0) unsafeAtomicAdd(&gpool[curg * HID + c], pacc);
  }
  unsafeAtomicAdd(&stats[c], lsum);
  unsafeAtomicAdd(&stats[HID + c], lsq);
}

// ---------------------------------------------------------------------------
// out[g,c] = scl_c * gpool[g,c] + cnt_g * sh_c  (BN affine commutes with pool)
__device__ __forceinline__ int lbound(const int* __restrict__ arr, int n,
                                      int key) {
  int lo = 0, hi = n;
  while (lo < hi) {
    int mid = (lo + hi) >> 1;
    if (arr[mid] < key) lo = mid + 1; else hi = mid;
  }
  return lo;
}

__global__ __launch_bounds__(128) void finish_kernel(
    const float* __restrict__ gpool, const float* __restrict__ stats,
    const float* __restrict__ gam, const float* __restrict__ bet,
    const int* __restrict__ batch, float* __restrict__ out) {
  __shared__ int cnt_s;
  int g = blockIdx.x, c = threadIdx.x;
  if (c == 0)
    cnt_s = lbound(batch, NNODES, g + 1) - lbound(batch, NNODES, g);
  __syncthreads();
  float mu = stats[c] * (1.0f / NNODES);
  float var = stats[HID + c] * (1.0f / NNODES) - mu * mu;
  float scl = gam[c] * rsqrtf(var + BN_EPS);
  float sh = bet[c] - mu * scl;
  out[g * HID + c] = fmaf(gpool[g * HID + c], scl, (float)cnt_s * sh);
}

// ---------------------------------------------------------------------------
extern "C" void kernel_launch(void* const* d_in, const int* in_sizes, int n_in,
                              void* d_out, int out_size, void* d_ws, size_t ws_size,
                              hipStream_t stream) {
  const int* x_idx = (const int*)d_in[0];
  const int* eidx = (const int*)d_in[1];   // [2, E]: src row then dst row
  const int* eattr = (const int*)d_in[2];
  const int* batch = (const int*)d_in[3];
  const float* node_emb = (const float*)d_in[4];
  const float* edge_emb = (const float*)d_in[5];
  const float* W1 = (const float*)d_in[6];
  const float* b1 = (const float*)d_in[7];
  const float* W2 = (const float*)d_in[8];
  const float* b2 = (const float*)d_in[9];
  const float* bn_g = (const float*)d_in[10];
  const float* bn_b = (const float*)d_in[11];
  float* out = (float*)d_out;

  const size_t nfeat = (size_t)NNODES * HID;
  float* x = (float*)d_ws;                   // [N,H] fp32
  float* h2 = x + nfeat;                     // [N,H] fp32
  float* stats0 = h2 + nfeat;                // [2,H]
  float* stats1 = stats0 + 2 * HID;          // [2,H]
  float* gpool = stats1 + 2 * HID;           // [G,H]
  int* deg = (int*)(gpool + NGRAPHS * HID);  // [N]
  int* offs = deg + NNODES;                  // [N+1]
  int* cursor = offs + (NNODES + 1);         // [N]
  int* csum = cursor + NNODES;               // [256]
  int* cbase = csum + 256;                   // [256]
  int* eout = cbase + 256;                   // [E]
  unsigned short* Wpk = (unsigned short*)(eout + NEDGES);  // hi[65536]+lo[65536]
  size_t needed = (size_t)((char*)(Wpk + 131072) - (char*)d_ws);
  if (ws_size < needed) return;  // fails validation loudly, doesn't corrupt

  // zero stats0, stats1, gpool, deg in one shot (contiguous)
  hipMemsetAsync(stats0, 0, (4 * HID + NGRAPHS * HID + NNODES) * sizeof(int),
                 stream);

  prep_kernel<<<1024, 256, 0, stream>>>(x_idx, node_emb, x, eidx, deg);
  wpack_kernel<<<256, 256, 0, stream>>>(W1, W2, Wpk);
  chunksum_kernel<<<256, 256, 0, stream>>>(deg, csum);
  scanbase_kernel<<<1, 256, 0, stream>>>(csum, cbase);
  scan2_kernel<<<256, 256, 0, stream>>>(deg, cbase, offs, cursor);
  scatter_kernel<<<(NEDGES + 255) / 256, 256, 0, stream>>>(eidx, eattr, cursor,
                                                           eout);

  const short8* Wfh = (const short8*)Wpk;          // 8192 frags (hi)
  const short8* Wfl = Wfh + 8192;                  // 8192 frags (lo)
  // layer 0: in = x (identity affine), out -> h2 fp32, stats0
  gine_mlp_kernel<<<GRID_GINE, 256, 0, stream>>>(
      x, nullptr, nullptr, nullptr, offs, eout, edge_emb,
      Wfh + 0 * 2048, Wfl + 0 * 2048, b1, b2, h2, stats0, nullptr, nullptr);
  // layer 1: in = h2 with BN(layer0) folded, out -> gpool + stats1
  gine_mlp_kernel<<<GRID_GINE, 256, 0, stream>>>(
      h2, stats0, bn_g, bn_b, offs, eout, edge_emb,
      Wfh + 2 * 2048, Wfl + 2 * 2048, b1 + HID, b2 + HID, nullptr, stats1,
      batch, gpool);
  // final: out = scl*gpool + cnt*sh
  finish_kernel<<<NGRAPHS, 128, 0, stream>>>(gpool, stats1, bn_g + HID,
                                             bn_b + HID, batch, out);
}

// Round 8
// 453.297 us; speedup vs baseline: 1.1742x; 1.1742x over previous
//
#include <hip/hip_runtime.h>
#include <hip/hip_bf16.h>

#define HID 128
#define NNODES 50000
#define NEDGES 800000
#define NGRAPHS 64
#define BN_EPS 1e-5f
#define SCAN_CHUNK 196  // 256*196 = 50176 >= 50000

typedef __attribute__((ext_vector_type(8))) short short8;   // 8 bf16 (4 VGPRs)
typedef __attribute__((ext_vector_type(4))) float f32x4;    // MFMA acc

static __device__ __forceinline__ unsigned short f2bf(float v) {
  __hip_bfloat16 b = __float2bfloat16(v);  // round-to-nearest
  return *reinterpret_cast<unsigned short*>(&b);
}
static __device__ __forceinline__ float bf2f(unsigned short u) {
  return __uint_as_float(((unsigned)u) << 16);
}

// split fp32 -> hi+lo bf16 pair (bf16x3 scheme), 8 contiguous LDS floats
static __device__ __forceinline__ void split8(const float* __restrict__ p,
                                              short8& hi, short8& lo) {
  #pragma unroll
  for (int j = 0; j < 8; j++) {
    float v = p[j];
    unsigned short h = f2bf(v);
    hi[j] = (short)h;
    lo[j] = (short)f2bf(v - bf2f(h));
  }
}

static __device__ __forceinline__ void acc_edge(float4& acc, const float4& x,
                                                const float4& scl,
                                                const float4& se) {
  acc.x += fmaxf(fmaf(x.x, scl.x, se.x), 0.0f);
  acc.y += fmaxf(fmaf(x.y, scl.y, se.y), 0.0f);
  acc.z += fmaxf(fmaf(x.z, scl.z, se.z), 0.0f);
  acc.w += fmaxf(fmaf(x.w, scl.w, se.w), 0.0f);
}

// ===========================================================================
// prep: x = node_emb[x_idx] (fp32 float4) + in-degree histogram + weight pack
// Wpk layout: hi at idx, lo at idx+65536; idx = (((m*8+t)*4+q)*64+l)*8+j,
// lane l holds W[k=(l>>4)*8+j+q*32][n=t*16+(l&15)], m = layer*2+{0:W1,1:W2}
// ===========================================================================
__global__ __launch_bounds__(256) void prep_kernel(
    const int* __restrict__ x_idx, const float* __restrict__ node_emb,
    float* __restrict__ x, const int* __restrict__ eidx,
    int* __restrict__ deg, const float* __restrict__ W1,
    const float* __restrict__ W2, unsigned short* __restrict__ Wpk) {
  int i = blockIdx.x * 256 + threadIdx.x;
  int stride = gridDim.x * 256;
  const float4* ne4 = (const float4*)node_emb;
  float4* x4 = (float4*)x;
  for (int t = i; t < NNODES * (HID / 4); t += stride) {
    int n = t >> 5;  // HID/4 == 32
    int c4 = t & 31;
    x4[t] = ne4[x_idx[n] * 32 + c4];
  }
  for (int t = i; t < NEDGES; t += stride)
    atomicAdd(&deg[eidx[NEDGES + t]], 1);
  for (int idx = i; idx < 65536; idx += stride) {
    int j = idx & 7;
    int l = (idx >> 3) & 63;
    int q = (idx >> 9) & 3;
    int t = (idx >> 11) & 7;
    int m = idx >> 14;
    int k = ((l >> 4) << 3) + j + (q << 5);
    int n = (t << 4) + (l & 15);
    int layer = m >> 1;
    const float* W = (m & 1) ? W2 : W1;
    float w = W[(size_t)layer * HID * HID + k * HID + n];
    unsigned short h = f2bf(w);
    Wpk[idx] = h;
    Wpk[idx + 65536] = f2bf(w - bf2f(h));
  }
}

// ===========================================================================
// CSR build (3-pass coalesced scan + scatter)
// ===========================================================================
__global__ __launch_bounds__(256) void chunksum_kernel(
    const int* __restrict__ deg, int* __restrict__ csum) {
  __shared__ int s[256];
  int b = blockIdx.x, t = threadIdx.x;
  int idx = b * SCAN_CHUNK + t;
  s[t] = (t < SCAN_CHUNK && idx < NNODES) ? deg[idx] : 0;
  __syncthreads();
  for (int off = 128; off > 0; off >>= 1) {
    if (t < off) s[t] += s[t + off];
    __syncthreads();
  }
  if (t == 0) csum[b] = s[0];
}

__global__ __launch_bounds__(256) void scanbase_kernel(
    const int* __restrict__ csum, int* __restrict__ cbase) {
  __shared__ int s[256];
  int t = threadIdx.x;
  int v = csum[t];
  s[t] = v;
  __syncthreads();
  for (int off = 1; off < 256; off <<= 1) {
    int u = (t >= off) ? s[t - off] : 0;
    __syncthreads();
    s[t] += u;
    __syncthreads();
  }
  cbase[t] = s[t] - v;  // exclusive
}

__global__ __launch_bounds__(256) void scan2_kernel(
    const int* __restrict__ deg, const int* __restrict__ cbase,
    int* __restrict__ offs, int* __restrict__ cursor) {
  __shared__ int s[256];
  int b = blockIdx.x, t = threadIdx.x;
  int idx = b * SCAN_CHUNK + t;
  int val = (t < SCAN_CHUNK && idx < NNODES) ? deg[idx] : 0;
  s[t] = val;
  __syncthreads();
  for (int off = 1; off < 256; off <<= 1) {
    int u = (t >= off) ? s[t - off] : 0;
    __syncthreads();
    s[t] += u;
    __syncthreads();
  }
  if (t < SCAN_CHUNK && idx < NNODES) {
    int excl = cbase[b] + s[t] - val;
    offs[idx] = excl;
    cursor[idx] = excl;
  }
  if (b == 0 && t == 0) offs[NNODES] = NEDGES;
}

__global__ __launch_bounds__(256) void scatter_kernel(
    const int* __restrict__ eidx, const int* __restrict__ eattr,
    int* __restrict__ cursor, int* __restrict__ eout) {
  int e = blockIdx.x * 256 + threadIdx.x;
  if (e >= NEDGES) return;
  int d = eidx[NEDGES + e];
  int pos = atomicAdd(&cursor[d], 1);
  eout[pos] = eidx[e] | (eattr[e] << 16);  // src<65536, attr<4
}

// ===========================================================================
// Fused GINE layer, bf16x3 MFMA MLP, float4 gather.
// Block = 256 thr (4 waves), node tile NT=32, ONE reused LDS buffer.
// Gather: wave w owns nodes [w*8, w*8+8); lane = (edge-slot grp = lane>>5,
//   channel-quad c4 = lane&31); one wave load = 2 full edge rows (1 KB).
// GEMM: mfma_f32_16x16x32_bf16 with hi/lo split (fp32-grade).
// ===========================================================================
#define NT 32
#define LDAF 132  // 128+4 floats: float4-aligned rows
#define GRID_GINE ((NNODES + NT - 1) / NT)  // 1563

__global__ __launch_bounds__(256, 8) void gine_mlp_kernel(
    const float* __restrict__ in, const float* __restrict__ instats,
    const float* __restrict__ gam, const float* __restrict__ bet,
    const int* __restrict__ offs, const int* __restrict__ eout,
    const float* __restrict__ edge_emb,
    const short8* __restrict__ Wh, const short8* __restrict__ Wl,
    const float* __restrict__ b1, const float* __restrict__ b2,
    float* __restrict__ out_f, float* __restrict__ stats,
    const int* __restrict__ batch, float* __restrict__ gpool) {
  __shared__ __align__(16) float hA[NT * LDAF];  // h0 -> h1 -> h2 (reused)
  __shared__ __align__(16) float sheL[4 * HID];  // sh[c] + edge_emb[a][c]

  const int tid = threadIdx.x;
  const int lane = tid & 63;
  const int wave = tid >> 6;
  const int base = blockIdx.x * NT;

  // ---- fill she table (BN-of-previous-layer shift folded into edge emb) ----
  for (int t = tid; t < 4 * HID; t += 256) {
    int c = t & 127;
    float shc = 0.0f;
    if (instats) {
      float mu = instats[c] * (1.0f / NNODES);
      float var = instats[HID + c] * (1.0f / NNODES) - mu * mu;
      float s = gam[c] * rsqrtf(var + BN_EPS);
      shc = bet[c] - mu * s;
    }
    sheL[t] = shc + edge_emb[t];
  }

  // ---- per-lane affine float4 (channels 4*c4 .. 4*c4+3) ----
  const int c4 = lane & 31;
  const int grp = lane >> 5;
  float4 scl4 = make_float4(1.f, 1.f, 1.f, 1.f);
  float4 sh4 = make_float4(0.f, 0.f, 0.f, 0.f);
  if (instats) {
    #pragma unroll
    for (int j = 0; j < 4; j++) {
      int c = c4 * 4 + j;
      float mu = instats[c] * (1.0f / NNODES);
      float var = instats[HID + c] * (1.0f / NNODES) - mu * mu;
      float s = gam[c] * rsqrtf(var + BN_EPS);
      ((float*)&scl4)[j] = s;
      ((float*)&sh4)[j] = bet[c] - mu * s;
    }
  }
  __syncthreads();  // sheL ready

  // ---- phase 1: gather (float4 rows, 2 edges per wave-instr) ----
  {
    const float4* in4 = (const float4*)in;
    const float4* sheL4 = (const float4*)sheL;
    int node0 = base + wave * 8;
    int eNext = offs[min(node0, NNODES)];
    for (int i = 0; i < 8; i++) {
      int node = node0 + i;
      int nrow = wave * 8 + i;
      float4 acc = make_float4(0.f, 0.f, 0.f, 0.f);
      if (node < NNODES) {
        int e0 = eNext;
        int e1 = offs[node + 1];
        eNext = e1;
        if (grp == 0) {
          float4 s = in4[node * 32 + c4];
          acc.x = fmaf(s.x, scl4.x, sh4.x);
          acc.y = fmaf(s.y, scl4.y, sh4.y);
          acc.z = fmaf(s.z, scl4.z, sh4.z);
          acc.w = fmaf(s.w, scl4.w, sh4.w);
        }
        int e = e0;
        for (; e + 4 <= e1; e += 4) {  // 4 edges: 2 per half-wave, unroll 2
          int pA = eout[e + grp];
          int pB = eout[e + 2 + grp];
          float4 xA = in4[(pA & 0xFFFF) * 32 + c4];
          float4 xB = in4[(pB & 0xFFFF) * 32 + c4];
          float4 seA = sheL4[((pA >> 16) << 5) + c4];
          float4 seB = sheL4[((pB >> 16) << 5) + c4];
          acc_edge(acc, xA, scl4, seA);
          acc_edge(acc, xB, scl4, seB);
        }
        if (e + 2 <= e1) {
          int pA = eout[e + grp];
          float4 xA = in4[(pA & 0xFFFF) * 32 + c4];
          float4 seA = sheL4[((pA >> 16) << 5) + c4];
          acc_edge(acc, xA, scl4, seA);
          e += 2;
        }
        if (e < e1 && grp == 0) {
          int pA = eout[e];
          float4 xA = in4[(pA & 0xFFFF) * 32 + c4];
          float4 seA = sheL4[((pA >> 16) << 5) + c4];
          acc_edge(acc, xA, scl4, seA);
        }
      }
      // combine the two half-wave partials (channels match across halves)
      acc.x += __shfl_xor(acc.x, 32);
      acc.y += __shfl_xor(acc.y, 32);
      acc.z += __shfl_xor(acc.z, 32);
      acc.w += __shfl_xor(acc.w, 32);
      if (grp == 0) *(float4*)&hA[nrow * LDAF + c4 * 4] = acc;
    }
  }
  __syncthreads();

  const int col = lane & 15;
  const int quad = lane >> 4;
  const int rbase = quad * 4;
  const int ch0 = wave * 32 + col;
  const int ch1 = ch0 + 16;
  const int aoff = quad * 8;

  // ---- phase 2: GEMM1 (hA @ W1 + b1, relu) -> back into hA ----
  {
    f32x4 a00 = {0.f, 0.f, 0.f, 0.f}, a01 = a00, a10 = a00, a11 = a00;
    #pragma unroll
    for (int q = 0; q < 4; q++) {
      int f0 = (wave * 2 + 0) * 256 + q * 64 + lane;
      int f1 = (wave * 2 + 1) * 256 + q * 64 + lane;
      short8 b0h = Wh[f0], b0l = Wl[f0];
      short8 b1h = Wh[f1], b1l = Wl[f1];
      short8 a0h, a0l, a1h, a1l;
      split8(&hA[col * LDAF + q * 32 + aoff], a0h, a0l);
      split8(&hA[(16 + col) * LDAF + q * 32 + aoff], a1h, a1l);
      a00 = __builtin_amdgcn_mfma_f32_16x16x32_bf16(a0h, b0h, a00, 0, 0, 0);
      a00 = __builtin_amdgcn_mfma_f32_16x16x32_bf16(a0l, b0h, a00, 0, 0, 0);
      a00 = __builtin_amdgcn_mfma_f32_16x16x32_bf16(a0h, b0l, a00, 0, 0, 0);
      a01 = __builtin_amdgcn_mfma_f32_16x16x32_bf16(a0h, b1h, a01, 0, 0, 0);
      a01 = __builtin_amdgcn_mfma_f32_16x16x32_bf16(a0l, b1h, a01, 0, 0, 0);
      a01 = __builtin_amdgcn_mfma_f32_16x16x32_bf16(a0h, b1l, a01, 0, 0, 0);
      a10 = __builtin_amdgcn_mfma_f32_16x16x32_bf16(a1h, b0h, a10, 0, 0, 0);
      a10 = __builtin_amdgcn_mfma_f32_16x16x32_bf16(a1l, b0h, a10, 0, 0, 0);
      a10 = __builtin_amdgcn_mfma_f32_16x16x32_bf16(a1h, b0l, a10, 0, 0, 0);
      a11 = __builtin_amdgcn_mfma_f32_16x16x32_bf16(a1h, b1h, a11, 0, 0, 0);
      a11 = __builtin_amdgcn_mfma_f32_16x16x32_bf16(a1l, b1h, a11, 0, 0, 0);
      a11 = __builtin_amdgcn_mfma_f32_16x16x32_bf16(a1h, b1l, a11, 0, 0, 0);
    }
    __syncthreads();  // all GEMM1 reads of hA complete
    float bb0 = b1[ch0], bb1 = b1[ch1];
    #pragma unroll
    for (int r = 0; r < 4; r++) {
      hA[(rbase + r) * LDAF + ch0] = fmaxf(a00[r] + bb0, 0.0f);
      hA[(rbase + r) * LDAF + ch1] = fmaxf(a01[r] + bb1, 0.0f);
      hA[(16 + rbase + r) * LDAF + ch0] = fmaxf(a10[r] + bb0, 0.0f);
      hA[(16 + rbase + r) * LDAF + ch1] = fmaxf(a11[r] + bb1, 0.0f);
    }
  }
  __syncthreads();

  // ---- phase 3: GEMM2 (h1 @ W2 + b2, relu) -> back into hA ----
  {
    f32x4 a00 = {0.f, 0.f, 0.f, 0.f}, a01 = a00, a10 = a00, a11 = a00;
    #pragma unroll
    for (int q = 0; q < 4; q++) {
      int f0 = 2048 + (wave * 2 + 0) * 256 + q * 64 + lane;
      int f1 = 2048 + (wave * 2 + 1) * 256 + q * 64 + lane;
      short8 b0h = Wh[f0], b0l = Wl[f0];
      short8 b1h = Wh[f1], b1l = Wl[f1];
      short8 a0h, a0l, a1h, a1l;
      split8(&hA[col * LDAF + q * 32 + aoff], a0h, a0l);
      split8(&hA[(16 + col) * LDAF + q * 32 + aoff], a1h, a1l);
      a00 = __builtin_amdgcn_mfma_f32_16x16x32_bf16(a0h, b0h, a00, 0, 0, 0);
      a00 = __builtin_amdgcn_mfma_f32_16x16x32_bf16(a0l, b0h, a00, 0, 0, 0);
      a00 = __builtin_amdgcn_mfma_f32_16x16x32_bf16(a0h, b0l, a00, 0, 0, 0);
      a01 = __builtin_amdgcn_mfma_f32_16x16x32_bf16(a0h, b1h, a01, 0, 0, 0);
      a01 = __builtin_amdgcn_mfma_f32_16x16x32_bf16(a0l, b1h, a01, 0, 0, 0);
      a01 = __builtin_amdgcn_mfma_f32_16x16x32_bf16(a0h, b1l, a01, 0, 0, 0);
      a10 = __builtin_amdgcn_mfma_f32_16x16x32_bf16(a1h, b0h, a10, 0, 0, 0);
      a10 = __builtin_amdgcn_mfma_f32_16x16x32_bf16(a1l, b0h, a10, 0, 0, 0);
      a10 = __builtin_amdgcn_mfma_f32_16x16x32_bf16(a1h, b0l, a10, 0, 0, 0);
      a11 = __builtin_amdgcn_mfma_f32_16x16x32_bf16(a1h, b1h, a11, 0, 0, 0);
      a11 = __builtin_amdgcn_mfma_f32_16x16x32_bf16(a1l, b1h, a11, 0, 0, 0);
      a11 = __builtin_amdgcn_mfma_f32_16x16x32_bf16(a1h, b1l, a11, 0, 0, 0);
    }
    __syncthreads();  // all GEMM2 reads complete
    float bb0 = b2[ch0], bb1 = b2[ch1];
    #pragma unroll
    for (int r = 0; r < 4; r++) {
      hA[(rbase + r) * LDAF + ch0] = fmaxf(a00[r] + bb0, 0.0f);
      hA[(rbase + r) * LDAF + ch1] = fmaxf(a01[r] + bb1, 0.0f);
      hA[(16 + rbase + r) * LDAF + ch0] = fmaxf(a10[r] + bb0, 0.0f);
      hA[(16 + rbase + r) * LDAF + ch1] = fmaxf(a11[r] + bb1, 0.0f);
    }
  }
  __syncthreads();

  // ---- phase 4: epilogue (h2 now in hA) ----
  const int c = tid & 127;
  const int yy = tid >> 7;
  float lsum = 0.0f, lsq = 0.0f;
  if (out_f) {
    #pragma unroll 4
    for (int i = 0; i < 16; i++) {
      int n = yy * 16 + i;
      int node = base + n;
      if (node < NNODES) {
        float v = hA[n * LDAF + c];
        out_f[node * HID + c] = v;
        lsum += v;
        lsq += v * v;
      }
    }
  } else {
    int curg = -1;
    float pacc = 0.0f;
    for (int i = 0; i < 16; i++) {
      int n = yy * 16 + i;
      int node = base + n;
      if (node < NNODES) {
        float v = hA[n * LDAF + c];
        lsum += v;
        lsq += v * v;
        int bg = batch[node];
        if (bg != curg) {
          if (curg >= 0) unsafeAtomicAdd(&gpool[curg * HID + c], pacc);
          curg = bg;
          pacc = 0.0f;
        }
        pacc += v;
      }
    }
    if (curg >= 0) unsafeAtomicAdd(&gpool[curg * HID + c], pacc);
  }
  unsafeAtomicAdd(&stats[c], lsum);
  unsafeAtomicAdd(&stats[HID + c], lsq);
}

// ---------------------------------------------------------------------------
// out[g,c] = scl_c * gpool[g,c] + cnt_g * sh_c  (BN affine commutes with pool)
__device__ __forceinline__ int lbound(const int* __restrict__ arr, int n,
                                      int key) {
  int lo = 0, hi = n;
  while (lo < hi) {
    int mid = (lo + hi) >> 1;
    if (arr[mid] < key) lo = mid + 1; else hi = mid;
  }
  return lo;
}

__global__ __launch_bounds__(128) void finish_kernel(
    const float* __restrict__ gpool, const float* __restrict__ stats,
    const float* __restrict__ gam, const float* __restrict__ bet,
    const int* __restrict__ batch, float* __restrict__ out) {
  __shared__ int cnt_s;
  int g = blockIdx.x, c = threadIdx.x;
  if (c == 0)
    cnt_s = lbound(batch, NNODES, g + 1) - lbound(batch, NNODES, g);
  __syncthreads();
  float mu = stats[c] * (1.0f / NNODES);
  float var = stats[HID + c] * (1.0f / NNODES) - mu * mu;
  float scl = gam[c] * rsqrtf(var + BN_EPS);
  float sh = bet[c] - mu * scl;
  out[g * HID + c] = fmaf(gpool[g * HID + c], scl, (float)cnt_s * sh);
}

// ---------------------------------------------------------------------------
extern "C" void kernel_launch(void* const* d_in, const int* in_sizes, int n_in,
                              void* d_out, int out_size, void* d_ws, size_t ws_size,
                              hipStream_t stream) {
  const int* x_idx = (const int*)d_in[0];
  const int* eidx = (const int*)d_in[1];   // [2, E]: src row then dst row
  const int* eattr = (const int*)d_in[2];
  const int* batch = (const int*)d_in[3];
  const float* node_emb = (const float*)d_in[4];
  const float* edge_emb = (const float*)d_in[5];
  const float* W1 = (const float*)d_in[6];
  const float* b1 = (const float*)d_in[7];
  const float* W2 = (const float*)d_in[8];
  const float* b2 = (const float*)d_in[9];
  const float* bn_g = (const float*)d_in[10];
  const float* bn_b = (const float*)d_in[11];
  float* out = (float*)d_out;

  const size_t nfeat = (size_t)NNODES * HID;
  float* x = (float*)d_ws;                   // [N,H] fp32
  float* h2 = x + nfeat;                     // [N,H] fp32
  float* stats0 = h2 + nfeat;                // [2,H]
  float* stats1 = stats0 + 2 * HID;          // [2,H]
  float* gpool = stats1 + 2 * HID;           // [G,H]
  int* deg = (int*)(gpool + NGRAPHS * HID);  // [N]
  int* offs = deg + NNODES;                  // [N+1]
  int* cursor = offs + (NNODES + 1);         // [N]
  int* csum = cursor + NNODES;               // [256]
  int* cbase = csum + 256;                   // [256]
  int* eout = cbase + 256;                   // [E]
  unsigned short* Wpk = (unsigned short*)(eout + NEDGES);  // hi[65536]+lo[65536]
  size_t needed = (size_t)((char*)(Wpk + 131072) - (char*)d_ws);
  if (ws_size < needed) return;  // fails validation loudly, doesn't corrupt

  // zero stats0, stats1, gpool, deg in one shot (contiguous)
  hipMemsetAsync(stats0, 0, (4 * HID + NGRAPHS * HID + NNODES) * sizeof(int),
                 stream);

  prep_kernel<<<1024, 256, 0, stream>>>(x_idx, node_emb, x, eidx, deg, W1, W2,
                                        Wpk);
  chunksum_kernel<<<256, 256, 0, stream>>>(deg, csum);
  scanbase_kernel<<<1, 256, 0, stream>>>(csum, cbase);
  scan2_kernel<<<256, 256, 0, stream>>>(deg, cbase, offs, cursor);
  scatter_kernel<<<(NEDGES + 255) / 256, 256, 0, stream>>>(eidx, eattr, cursor,
                                                           eout);

  const short8* Wfh = (const short8*)Wpk;  // 8192 frags (hi)
  const short8* Wfl = Wfh + 8192;          // 8192 frags (lo)
  // layer 0: in = x (identity affine), out -> h2 fp32, stats0
  gine_mlp_kernel<<<GRID_GINE, 256, 0, stream>>>(
      x, nullptr, nullptr, nullptr, offs, eout, edge_emb,
      Wfh + 0 * 2048, Wfl + 0 * 2048, b1, b2, h2, stats0, nullptr, nullptr);
  // layer 1: in = h2 with BN(layer0) folded, out -> gpool + stats1
  gine_mlp_kernel<<<GRID_GINE, 256, 0, stream>>>(
      h2, stats0, bn_g, bn_b, offs, eout, edge_emb,
      Wfh + 2 * 2048, Wfl + 2 * 2048, b1 + HID, b2 + HID, nullptr, stats1,
      batch, gpool);
  // final: out = scl*gpool + cnt*sh
  finish_kernel<<<NGRAPHS, 128, 0, stream>>>(gpool, stats1, bn_g + HID,
                                             bn_b + HID, batch, out);
}

// Round 9
// 444.084 us; speedup vs baseline: 1.1985x; 1.0207x over previous
//
#include <hip/hip_runtime.h>
#include <hip/hip_bf16.h>

#define HID 128
#define NNODES 50000
#define NEDGES 800000
#define NGRAPHS 64
#define BN_EPS 1e-5f
#define SCAN_CHUNK 196  // 256*196 = 50176 >= 50000

typedef __attribute__((ext_vector_type(8))) short short8;   // 8 bf16 (4 VGPRs)
typedef __attribute__((ext_vector_type(4))) float f32x4;    // MFMA acc

static __device__ __forceinline__ unsigned short f2bf(float v) {
  __hip_bfloat16 b = __float2bfloat16(v);  // round-to-nearest
  return *reinterpret_cast<unsigned short*>(&b);
}
static __device__ __forceinline__ float bf2f(unsigned short u) {
  return __uint_as_float(((unsigned)u) << 16);
}

// split fp32 -> hi+lo bf16 pair (bf16x3 scheme), 8 contiguous LDS floats
static __device__ __forceinline__ void split8(const float* __restrict__ p,
                                              short8& hi, short8& lo) {
  #pragma unroll
  for (int j = 0; j < 8; j++) {
    float v = p[j];
    unsigned short h = f2bf(v);
    hi[j] = (short)h;
    lo[j] = (short)f2bf(v - bf2f(h));
  }
}

// ===========================================================================
// prep: xbf = bf16(node_emb[x_idx]) (packed pair writes) + in-degree
// histogram + weight pack (MFMA B-frag layout, hi/lo split).
// Wpk: hi at idx, lo at idx+65536; idx=(((m*8+t)*4+q)*64+l)*8+j,
// lane l holds W[k=(l>>4)*8+j+q*32][n=t*16+(l&15)], m=layer*2+{0:W1,1:W2}
// ===========================================================================
__global__ __launch_bounds__(256) void prep_kernel(
    const int* __restrict__ x_idx, const float* __restrict__ node_emb,
    unsigned int* __restrict__ xb2, const int* __restrict__ eidx,
    int* __restrict__ deg, const float* __restrict__ W1,
    const float* __restrict__ W2, unsigned short* __restrict__ Wpk) {
  int i = blockIdx.x * 256 + threadIdx.x;
  int stride = gridDim.x * 256;
  const float2* ne2 = (const float2*)node_emb;
  for (int t = i; t < NNODES * (HID / 2); t += stride) {
    int n = t >> 6;  // HID/2 == 64
    int c2 = t & 63;
    float2 v = ne2[x_idx[n] * 64 + c2];
    xb2[t] = (unsigned)f2bf(v.x) | ((unsigned)f2bf(v.y) << 16);
  }
  for (int t = i; t < NEDGES; t += stride)
    atomicAdd(&deg[eidx[NEDGES + t]], 1);
  for (int idx = i; idx < 65536; idx += stride) {
    int j = idx & 7;
    int l = (idx >> 3) & 63;
    int q = (idx >> 9) & 3;
    int t = (idx >> 11) & 7;
    int m = idx >> 14;
    int k = ((l >> 4) << 3) + j + (q << 5);
    int n = (t << 4) + (l & 15);
    int layer = m >> 1;
    const float* W = (m & 1) ? W2 : W1;
    float w = W[(size_t)layer * HID * HID + k * HID + n];
    unsigned short h = f2bf(w);
    Wpk[idx] = h;
    Wpk[idx + 65536] = f2bf(w - bf2f(h));
  }
}

// ===========================================================================
// CSR build (3-pass coalesced scan + scatter)
// ===========================================================================
__global__ __launch_bounds__(256) void chunksum_kernel(
    const int* __restrict__ deg, int* __restrict__ csum) {
  __shared__ int s[256];
  int b = blockIdx.x, t = threadIdx.x;
  int idx = b * SCAN_CHUNK + t;
  s[t] = (t < SCAN_CHUNK && idx < NNODES) ? deg[idx] : 0;
  __syncthreads();
  for (int off = 128; off > 0; off >>= 1) {
    if (t < off) s[t] += s[t + off];
    __syncthreads();
  }
  if (t == 0) csum[b] = s[0];
}

__global__ __launch_bounds__(256) void scanbase_kernel(
    const int* __restrict__ csum, int* __restrict__ cbase) {
  __shared__ int s[256];
  int t = threadIdx.x;
  int v = csum[t];
  s[t] = v;
  __syncthreads();
  for (int off = 1; off < 256; off <<= 1) {
    int u = (t >= off) ? s[t - off] : 0;
    __syncthreads();
    s[t] += u;
    __syncthreads();
  }
  cbase[t] = s[t] - v;  // exclusive
}

__global__ __launch_bounds__(256) void scan2_kernel(
    const int* __restrict__ deg, const int* __restrict__ cbase,
    int* __restrict__ offs, int* __restrict__ cursor) {
  __shared__ int s[256];
  int b = blockIdx.x, t = threadIdx.x;
  int idx = b * SCAN_CHUNK + t;
  int val = (t < SCAN_CHUNK && idx < NNODES) ? deg[idx] : 0;
  s[t] = val;
  __syncthreads();
  for (int off = 1; off < 256; off <<= 1) {
    int u = (t >= off) ? s[t - off] : 0;
    __syncthreads();
    s[t] += u;
    __syncthreads();
  }
  if (t < SCAN_CHUNK && idx < NNODES) {
    int excl = cbase[b] + s[t] - val;
    offs[idx] = excl;
    cursor[idx] = excl;
  }
  if (b == 0 && t == 0) offs[NNODES] = NEDGES;
}

__global__ __launch_bounds__(256) void scatter_kernel(
    const int* __restrict__ eidx, const int* __restrict__ eattr,
    int* __restrict__ cursor, int* __restrict__ eout) {
  int e = blockIdx.x * 256 + threadIdx.x;
  if (e >= NEDGES) return;
  int d = eidx[NEDGES + e];
  int pos = atomicAdd(&cursor[d], 1);
  eout[pos] = eidx[e] | (eattr[e] << 16);  // src<65536, attr<4
}

// ===========================================================================
// Fused GINE layer. bf16 features (16B/lane gather: 4 edge rows per wave
// instr), fp32 gather math, bf16x3 MFMA MLP (fp32-grade GEMM).
// Block = 256 (4 waves), NT=32 nodes, one reused LDS hA buffer.
// Gather lanes: c8 = lane&15 (channel octet), grp = lane>>4 (edge slot 0..3).
// ===========================================================================
#define NT 32
#define LDAF 132  // 128+4 floats: float4-aligned rows
#define GRID_GINE ((NNODES + NT - 1) / NT)  // 1563

__global__ __launch_bounds__(256, 6) void gine_mlp_kernel(
    const unsigned short* __restrict__ in_bf,
    const float* __restrict__ instats,
    const float* __restrict__ gam, const float* __restrict__ bet,
    const int* __restrict__ offs, const int* __restrict__ eout,
    const float* __restrict__ edge_emb,
    const short8* __restrict__ Wh, const short8* __restrict__ Wl,
    const float* __restrict__ b1, const float* __restrict__ b2,
    unsigned short* __restrict__ out_bf, float* __restrict__ stats,
    const int* __restrict__ batch, float* __restrict__ gpool) {
  __shared__ __align__(16) float hA[NT * LDAF];  // h0 -> h1 -> h2 (reused)
  __shared__ __align__(16) float sheL[4 * HID];  // sh[c] + edge_emb[a][c]

  const int tid = threadIdx.x;
  const int lane = tid & 63;
  const int wave = tid >> 6;
  const int base = blockIdx.x * NT;

  // ---- fill she table (BN shift of previous layer folded into edge emb) ----
  for (int t = tid; t < 4 * HID; t += 256) {
    int c = t & 127;
    float shc = 0.0f;
    if (instats) {
      float mu = instats[c] * (1.0f / NNODES);
      float var = instats[HID + c] * (1.0f / NNODES) - mu * mu;
      float s = gam[c] * rsqrtf(var + BN_EPS);
      shc = bet[c] - mu * s;
    }
    sheL[t] = shc + edge_emb[t];
  }

  // ---- per-lane affine over 8 channels (c8*8 .. c8*8+7) ----
  const int c8 = lane & 15;
  const int grp = lane >> 4;
  float scl8[8], sh8[8];
  #pragma unroll
  for (int j = 0; j < 8; j++) { scl8[j] = 1.0f; sh8[j] = 0.0f; }
  if (instats) {
    #pragma unroll
    for (int j = 0; j < 8; j++) {
      int c = c8 * 8 + j;
      float mu = instats[c] * (1.0f / NNODES);
      float var = instats[HID + c] * (1.0f / NNODES) - mu * mu;
      float s = gam[c] * rsqrtf(var + BN_EPS);
      scl8[j] = s;
      sh8[j] = bet[c] - mu * s;
    }
  }
  __syncthreads();  // sheL ready

  // ---- phase 1: gather (bf16 rows, 16B/lane, 4 edges per wave instr) ----
  {
    const short8* in8 = (const short8*)in_bf;  // row = 16 short8s
    int node0 = base + wave * 8;
    int eNext = offs[min(node0, NNODES)];
    for (int i = 0; i < 8; i++) {
      int node = node0 + i;
      int nrow = wave * 8 + i;
      float acc[8];
      #pragma unroll
      for (int j = 0; j < 8; j++) acc[j] = 0.0f;
      if (node < NNODES) {
        int e0 = eNext;
        int e1 = offs[node + 1];
        eNext = e1;
        if (grp == 0) {
          short8 s = in8[node * 16 + c8];
          #pragma unroll
          for (int j = 0; j < 8; j++)
            acc[j] = fmaf(bf2f((unsigned short)s[j]), scl8[j], sh8[j]);
        }
        int e = e0;
        for (; e + 8 <= e1; e += 8) {  // 8 edges: 2 per slot
          int pA = eout[e + grp];
          int pB = eout[e + 4 + grp];
          short8 xA = in8[(pA & 0xFFFF) * 16 + c8];
          short8 xB = in8[(pB & 0xFFFF) * 16 + c8];
          const float4* sA = (const float4*)&sheL[((pA >> 16) << 7) + c8 * 8];
          const float4* sB = (const float4*)&sheL[((pB >> 16) << 7) + c8 * 8];
          float4 sA0 = sA[0], sA1 = sA[1], sB0 = sB[0], sB1 = sB[1];
          #pragma unroll
          for (int j = 0; j < 8; j++) {
            float seA = (j < 4) ? ((const float*)&sA0)[j] : ((const float*)&sA1)[j - 4];
            float seB = (j < 4) ? ((const float*)&sB0)[j] : ((const float*)&sB1)[j - 4];
            acc[j] += fmaxf(fmaf(bf2f((unsigned short)xA[j]), scl8[j], seA), 0.0f) +
                      fmaxf(fmaf(bf2f((unsigned short)xB[j]), scl8[j], seB), 0.0f);
          }
        }
        if (e + 4 <= e1) {
          int pA = eout[e + grp];
          short8 xA = in8[(pA & 0xFFFF) * 16 + c8];
          const float4* sA = (const float4*)&sheL[((pA >> 16) << 7) + c8 * 8];
          float4 sA0 = sA[0], sA1 = sA[1];
          #pragma unroll
          for (int j = 0; j < 8; j++) {
            float seA = (j < 4) ? ((const float*)&sA0)[j] : ((const float*)&sA1)[j - 4];
            acc[j] += fmaxf(fmaf(bf2f((unsigned short)xA[j]), scl8[j], seA), 0.0f);
          }
          e += 4;
        }
        int rem = e1 - e;  // 0..3
        if (grp < rem) {
          int pA = eout[e + grp];
          short8 xA = in8[(pA & 0xFFFF) * 16 + c8];
          const float4* sA = (const float4*)&sheL[((pA >> 16) << 7) + c8 * 8];
          float4 sA0 = sA[0], sA1 = sA[1];
          #pragma unroll
          for (int j = 0; j < 8; j++) {
            float seA = (j < 4) ? ((const float*)&sA0)[j] : ((const float*)&sA1)[j - 4];
            acc[j] += fmaxf(fmaf(bf2f((unsigned short)xA[j]), scl8[j], seA), 0.0f);
          }
        }
      }
      // combine the 4 edge-slot partials (same channels across slots)
      #pragma unroll
      for (int j = 0; j < 8; j++) {
        acc[j] += __shfl_xor(acc[j], 16);
        acc[j] += __shfl_xor(acc[j], 32);
      }
      if (grp == 0) {
        float4 lo = make_float4(acc[0], acc[1], acc[2], acc[3]);
        float4 hi = make_float4(acc[4], acc[5], acc[6], acc[7]);
        *(float4*)&hA[nrow * LDAF + c8 * 8] = lo;
        *(float4*)&hA[nrow * LDAF + c8 * 8 + 4] = hi;
      }
    }
  }
  __syncthreads();

  const int col = lane & 15;
  const int quad = lane >> 4;
  const int rbase = quad * 4;
  const int ch0 = wave * 32 + col;
  const int ch1 = ch0 + 16;
  const int aoff = quad * 8;

  // ---- phase 2: GEMM1 (hA @ W1 + b1, relu) -> back into hA ----
  {
    f32x4 a00 = {0.f, 0.f, 0.f, 0.f}, a01 = a00, a10 = a00, a11 = a00;
    #pragma unroll
    for (int q = 0; q < 4; q++) {
      int f0 = (wave * 2 + 0) * 256 + q * 64 + lane;
      int f1 = (wave * 2 + 1) * 256 + q * 64 + lane;
      short8 b0h = Wh[f0], b0l = Wl[f0];
      short8 b1h = Wh[f1], b1l = Wl[f1];
      short8 a0h, a0l, a1h, a1l;
      split8(&hA[col * LDAF + q * 32 + aoff], a0h, a0l);
      split8(&hA[(16 + col) * LDAF + q * 32 + aoff], a1h, a1l);
      a00 = __builtin_amdgcn_mfma_f32_16x16x32_bf16(a0h, b0h, a00, 0, 0, 0);
      a00 = __builtin_amdgcn_mfma_f32_16x16x32_bf16(a0l, b0h, a00, 0, 0, 0);
      a00 = __builtin_amdgcn_mfma_f32_16x16x32_bf16(a0h, b0l, a00, 0, 0, 0);
      a01 = __builtin_amdgcn_mfma_f32_16x16x32_bf16(a0h, b1h, a01, 0, 0, 0);
      a01 = __builtin_amdgcn_mfma_f32_16x16x32_bf16(a0l, b1h, a01, 0, 0, 0);
      a01 = __builtin_amdgcn_mfma_f32_16x16x32_bf16(a0h, b1l, a01, 0, 0, 0);
      a10 = __builtin_amdgcn_mfma_f32_16x16x32_bf16(a1h, b0h, a10, 0, 0, 0);
      a10 = __builtin_amdgcn_mfma_f32_16x16x32_bf16(a1l, b0h, a10, 0, 0, 0);
      a10 = __builtin_amdgcn_mfma_f32_16x16x32_bf16(a1h, b0l, a10, 0, 0, 0);
      a11 = __builtin_amdgcn_mfma_f32_16x16x32_bf16(a1h, b1h, a11, 0, 0, 0);
      a11 = __builtin_amdgcn_mfma_f32_16x16x32_bf16(a1l, b1h, a11, 0, 0, 0);
      a11 = __builtin_amdgcn_mfma_f32_16x16x32_bf16(a1h, b1l, a11, 0, 0, 0);
    }
    __syncthreads();  // all GEMM1 reads of hA complete
    float bb0 = b1[ch0], bb1 = b1[ch1];
    #pragma unroll
    for (int r = 0; r < 4; r++) {
      hA[(rbase + r) * LDAF + ch0] = fmaxf(a00[r] + bb0, 0.0f);
      hA[(rbase + r) * LDAF + ch1] = fmaxf(a01[r] + bb1, 0.0f);
      hA[(16 + rbase + r) * LDAF + ch0] = fmaxf(a10[r] + bb0, 0.0f);
      hA[(16 + rbase + r) * LDAF + ch1] = fmaxf(a11[r] + bb1, 0.0f);
    }
  }
  __syncthreads();

  // ---- phase 3: GEMM2 (h1 @ W2 + b2, relu) -> back into hA ----
  {
    f32x4 a00 = {0.f, 0.f, 0.f, 0.f}, a01 = a00, a10 = a00, a11 = a00;
    #pragma unroll
    for (int q = 0; q < 4; q++) {
      int f0 = 2048 + (wave * 2 + 0) * 256 + q * 64 + lane;
      int f1 = 2048 + (wave * 2 + 1) * 256 + q * 64 + lane;
      short8 b0h = Wh[f0], b0l = Wl[f0];
      short8 b1h = Wh[f1], b1l = Wl[f1];
      short8 a0h, a0l, a1h, a1l;
      split8(&hA[col * LDAF + q * 32 + aoff], a0h, a0l);
      split8(&hA[(16 + col) * LDAF + q * 32 + aoff], a1h, a1l);
      a00 = __builtin_amdgcn_mfma_f32_16x16x32_bf16(a0h, b0h, a00, 0, 0, 0);
      a00 = __builtin_amdgcn_mfma_f32_16x16x32_bf16(a0l, b0h, a00, 0, 0, 0);
      a00 = __builtin_amdgcn_mfma_f32_16x16x32_bf16(a0h, b0l, a00, 0, 0, 0);
      a01 = __builtin_amdgcn_mfma_f32_16x16x32_bf16(a0h, b1h, a01, 0, 0, 0);
      a01 = __builtin_amdgcn_mfma_f32_16x16x32_bf16(a0l, b1h, a01, 0, 0, 0);
      a01 = __builtin_amdgcn_mfma_f32_16x16x32_bf16(a0h, b1l, a01, 0, 0, 0);
      a10 = __builtin_amdgcn_mfma_f32_16x16x32_bf16(a1h, b0h, a10, 0, 0, 0);
      a10 = __builtin_amdgcn_mfma_f32_16x16x32_bf16(a1l, b0h, a10, 0, 0, 0);
      a10 = __builtin_amdgcn_mfma_f32_16x16x32_bf16(a1h, b0l, a10, 0, 0, 0);
      a11 = __builtin_amdgcn_mfma_f32_16x16x32_bf16(a1h, b1h, a11, 0, 0, 0);
      a11 = __builtin_amdgcn_mfma_f32_16x16x32_bf16(a1l, b1h, a11, 0, 0, 0);
      a11 = __builtin_amdgcn_mfma_f32_16x16x32_bf16(a1h, b1l, a11, 0, 0, 0);
    }
    __syncthreads();  // all GEMM2 reads complete
    float bb0 = b2[ch0], bb1 = b2[ch1];
    #pragma unroll
    for (int r = 0; r < 4; r++) {
      hA[(rbase + r) * LDAF + ch0] = fmaxf(a00[r] + bb0, 0.0f);
      hA[(rbase + r) * LDAF + ch1] = fmaxf(a01[r] + bb1, 0.0f);
      hA[(16 + rbase + r) * LDAF + ch0] = fmaxf(a10[r] + bb0, 0.0f);
      hA[(16 + rbase + r) * LDAF + ch1] = fmaxf(a11[r] + bb1, 0.0f);
    }
  }
  __syncthreads();

  // ---- phase 4: epilogue (h2 now in hA) ----
  const int c = tid & 127;
  const int yy = tid >> 7;
  float lsum = 0.0f, lsq = 0.0f;
  if (out_bf) {
    #pragma unroll 4
    for (int i = 0; i < 16; i++) {
      int n = yy * 16 + i;
      int node = base + n;
      if (node < NNODES) {
        float v = hA[n * LDAF + c];
        out_bf[node * HID + c] = f2bf(v);
        lsum += v;
        lsq += v * v;
      }
    }
  } else {
    int curg = -1;
    float pacc = 0.0f;
    for (int i = 0; i < 16; i++) {
      int n = yy * 16 + i;
      int node = base + n;
      if (node < NNODES) {
        float v = hA[n * LDAF + c];
        lsum += v;
        lsq += v * v;
        int bg = batch[node];
        if (bg != curg) {
          if (curg >= 0) unsafeAtomicAdd(&gpool[curg * HID + c], pacc);
          curg = bg;
          pacc = 0.0f;
        }
        pacc += v;
      }
    }
    if (curg >= 0) unsafeAtomicAdd(&gpool[curg * HID + c], pacc);
  }
  unsafeAtomicAdd(&stats[c], lsum);
  unsafeAtomicAdd(&stats[HID + c], lsq);
}

// ---------------------------------------------------------------------------
// out[g,c] = scl_c * gpool[g,c] + cnt_g * sh_c  (BN affine commutes with pool)
__device__ __forceinline__ int lbound(const int* __restrict__ arr, int n,
                                      int key) {
  int lo = 0, hi = n;
  while (lo < hi) {
    int mid = (lo + hi) >> 1;
    if (arr[mid] < key) lo = mid + 1; else hi = mid;
  }
  return lo;
}

__global__ __launch_bounds__(128) void finish_kernel(
    const float* __restrict__ gpool, const float* __restrict__ stats,
    const float* __restrict__ gam, const float* __restrict__ bet,
    const int* __restrict__ batch, float* __restrict__ out) {
  __shared__ int cnt_s;
  int g = blockIdx.x, c = threadIdx.x;
  if (c == 0)
    cnt_s = lbound(batch, NNODES, g + 1) - lbound(batch, NNODES, g);
  __syncthreads();
  float mu = stats[c] * (1.0f / NNODES);
  float var = stats[HID + c] * (1.0f / NNODES) - mu * mu;
  float scl = gam[c] * rsqrtf(var + BN_EPS);
  float sh = bet[c] - mu * scl;
  out[g * HID + c] = fmaf(gpool[g * HID + c], scl, (float)cnt_s * sh);
}

// ---------------------------------------------------------------------------
extern "C" void kernel_launch(void* const* d_in, const int* in_sizes, int n_in,
                              void* d_out, int out_size, void* d_ws, size_t ws_size,
                              hipStream_t stream) {
  const int* x_idx = (const int*)d_in[0];
  const int* eidx = (const int*)d_in[1];   // [2, E]: src row then dst row
  const int* eattr = (const int*)d_in[2];
  const int* batch = (const int*)d_in[3];
  const float* node_emb = (const float*)d_in[4];
  const float* edge_emb = (const float*)d_in[5];
  const float* W1 = (const float*)d_in[6];
  const float* b1 = (const float*)d_in[7];
  const float* W2 = (const float*)d_in[8];
  const float* b2 = (const float*)d_in[9];
  const float* bn_g = (const float*)d_in[10];
  const float* bn_b = (const float*)d_in[11];
  float* out = (float*)d_out;

  const size_t nfeat = (size_t)NNODES * HID;
  unsigned short* xbf = (unsigned short*)d_ws;  // [N,H] bf16
  unsigned short* h2bf = xbf + nfeat;           // [N,H] bf16
  float* stats0 = (float*)(h2bf + nfeat);       // [2,H]
  float* stats1 = stats0 + 2 * HID;             // [2,H]
  float* gpool = stats1 + 2 * HID;              // [G,H]
  int* deg = (int*)(gpool + NGRAPHS * HID);     // [N]
  int* offs = deg + NNODES;                     // [N+1]
  int* cursor = offs + (NNODES + 1);            // [N]
  int* csum = cursor + NNODES;                  // [256]
  int* cbase = csum + 256;                      // [256]
  int* eout = cbase + 256;                      // [E]
  unsigned short* Wpk = (unsigned short*)(eout + NEDGES);  // hi+lo [131072]
  size_t needed = (size_t)((char*)(Wpk + 131072) - (char*)d_ws);
  if (ws_size < needed) return;  // fails validation loudly, doesn't corrupt

  // zero stats0, stats1, gpool, deg in one shot (contiguous)
  hipMemsetAsync(stats0, 0, (4 * HID + NGRAPHS * HID + NNODES) * sizeof(int),
                 stream);

  prep_kernel<<<1024, 256, 0, stream>>>(x_idx, node_emb, (unsigned int*)xbf,
                                        eidx, deg, W1, W2, Wpk);
  chunksum_kernel<<<256, 256, 0, stream>>>(deg, csum);
  scanbase_kernel<<<1, 256, 0, stream>>>(csum, cbase);
  scan2_kernel<<<256, 256, 0, stream>>>(deg, cbase, offs, cursor);
  scatter_kernel<<<(NEDGES + 255) / 256, 256, 0, stream>>>(eidx, eattr, cursor,
                                                           eout);

  const short8* Wfh = (const short8*)Wpk;  // 8192 frags (hi)
  const short8* Wfl = Wfh + 8192;          // 8192 frags (lo)
  // layer 0: in = xbf (identity affine), out -> h2bf, stats0
  gine_mlp_kernel<<<GRID_GINE, 256, 0, stream>>>(
      xbf, nullptr, nullptr, nullptr, offs, eout, edge_emb,
      Wfh + 0 * 2048, Wfl + 0 * 2048, b1, b2, h2bf, stats0, nullptr, nullptr);
  // layer 1: in = h2bf with BN(layer0) folded, out -> gpool + stats1
  gine_mlp_kernel<<<GRID_GINE, 256, 0, stream>>>(
      h2bf, stats0, bn_g, bn_b, offs, eout, edge_emb,
      Wfh + 2 * 2048, Wfl + 2 * 2048, b1 + HID, b2 + HID, nullptr, stats1,
      batch, gpool);
  // final: out = scl*gpool + cnt*sh
  finish_kernel<<<NGRAPHS, 128, 0, stream>>>(gpool, stats1, bn_g + HID,
                                             bn_b + HID, batch, out);
}

// Round 10
// 378.357 us; speedup vs baseline: 1.4067x; 1.1737x over previous
//
#include <hip/hip_runtime.h>
#include <hip/hip_bf16.h>

#define HID 128
#define NNODES 50000
#define NEDGES 800000
#define NGRAPHS 64
#define BN_EPS 1e-5f
#define CAP 64  // bucket capacity; deg ~ Poisson(16), P(deg>63) ~ 1e-21

typedef __attribute__((ext_vector_type(8))) short short8;   // 8 bf16 (4 VGPRs)
typedef __attribute__((ext_vector_type(4))) float f32x4;    // MFMA acc

static __device__ __forceinline__ unsigned short f2bf(float v) {
  __hip_bfloat16 b = __float2bfloat16(v);  // round-to-nearest
  return *reinterpret_cast<unsigned short*>(&b);
}
static __device__ __forceinline__ float bf2f(unsigned short u) {
  return __uint_as_float(((unsigned)u) << 16);
}

// split fp32 -> hi+lo bf16 pair (bf16x3 scheme), 8 contiguous LDS floats
static __device__ __forceinline__ void split8(const float* __restrict__ p,
                                              short8& hi, short8& lo) {
  #pragma unroll
  for (int j = 0; j < 8; j++) {
    float v = p[j];
    unsigned short h = f2bf(v);
    hi[j] = (short)h;
    lo[j] = (short)f2bf(v - bf2f(h));
  }
}

// ===========================================================================
// prep (single kernel): xbf = bf16(node_emb[x_idx]) + bucket-CSR build +
// weight pack (MFMA B-frag layout, hi/lo split).
// Bucket: pos = atomicAdd(cnt[dst]); eout[dst*CAP+pos] = src|(attr<<16).
// Wpk: hi at idx, lo at idx+65536; idx=(((m*8+t)*4+q)*64+l)*8+j,
// lane l holds W[k=(l>>4)*8+j+q*32][n=t*16+(l&15)], m=layer*2+{0:W1,1:W2}
// ===========================================================================
__global__ __launch_bounds__(256) void prep_kernel(
    const int* __restrict__ x_idx, const float* __restrict__ node_emb,
    unsigned int* __restrict__ xb2, const int* __restrict__ eidx,
    const int* __restrict__ eattr, int* __restrict__ cnt,
    int* __restrict__ eout, const float* __restrict__ W1,
    const float* __restrict__ W2, unsigned short* __restrict__ Wpk) {
  int i = blockIdx.x * 256 + threadIdx.x;
  int stride = gridDim.x * 256;
  const float2* ne2 = (const float2*)node_emb;
  for (int t = i; t < NNODES * (HID / 2); t += stride) {
    int n = t >> 6;  // HID/2 == 64
    int c2 = t & 63;
    float2 v = ne2[x_idx[n] * 64 + c2];
    xb2[t] = (unsigned)f2bf(v.x) | ((unsigned)f2bf(v.y) << 16);
  }
  for (int e = i; e < NEDGES; e += stride) {
    int d = eidx[NEDGES + e];
    int pos = atomicAdd(&cnt[d], 1);
    if (pos < CAP) eout[((size_t)d << 6) + pos] = eidx[e] | (eattr[e] << 16);
  }
  for (int idx = i; idx < 65536; idx += stride) {
    int j = idx & 7;
    int l = (idx >> 3) & 63;
    int q = (idx >> 9) & 3;
    int t = (idx >> 11) & 7;
    int m = idx >> 14;
    int k = ((l >> 4) << 3) + j + (q << 5);
    int n = (t << 4) + (l & 15);
    int layer = m >> 1;
    const float* W = (m & 1) ? W2 : W1;
    float w = W[(size_t)layer * HID * HID + k * HID + n];
    unsigned short h = f2bf(w);
    Wpk[idx] = h;
    Wpk[idx + 65536] = f2bf(w - bf2f(h));
  }
}

// ===========================================================================
// Fused GINE layer. 512 threads (8 waves) per block, NT=32 nodes.
// Gather: wave w owns nodes [w*4, w*4+4); lanes = 16 ch-octets x 4 edge
// slots; one wave load = 4 edge rows (bf16, 16B/lane).
// GEMM: wave w computes ch-tile w (16 channels) x 2 row-tiles via
// mfma_f32_16x16x32_bf16 with hi/lo split (fp32-grade).
// Epilogue: first 256 threads (thread = channel, 16 nodes each).
// ===========================================================================
#define NT 32
#define LDAF 132  // 128+4 floats: float4-aligned rows
#define GRID_GINE ((NNODES + NT - 1) / NT)  // 1563

__global__ __launch_bounds__(512, 8) void gine_mlp_kernel(
    const unsigned short* __restrict__ in_bf,
    const float* __restrict__ instats,
    const float* __restrict__ gam, const float* __restrict__ bet,
    const int* __restrict__ cnt, const int* __restrict__ eout,
    const float* __restrict__ edge_emb,
    const short8* __restrict__ Wh, const short8* __restrict__ Wl,
    const float* __restrict__ b1, const float* __restrict__ b2,
    unsigned short* __restrict__ out_bf, float* __restrict__ stats,
    const int* __restrict__ batch, float* __restrict__ gpool) {
  __shared__ __align__(16) float hA[NT * LDAF];  // h0 -> h1 -> h2 (reused)
  __shared__ __align__(16) float sheL[4 * HID];  // sh[c] + edge_emb[a][c]

  const int tid = threadIdx.x;
  const int lane = tid & 63;
  const int wave = tid >> 6;   // 0..7
  const int base = blockIdx.x * NT;

  // ---- fill she table (BN shift of previous layer folded into edge emb) ----
  if (tid < 4 * HID) {
    int c = tid & 127;
    float shc = 0.0f;
    if (instats) {
      float mu = instats[c] * (1.0f / NNODES);
      float var = instats[HID + c] * (1.0f / NNODES) - mu * mu;
      float s = gam[c] * rsqrtf(var + BN_EPS);
      shc = bet[c] - mu * s;
    }
    sheL[tid] = shc + edge_emb[tid];
  }

  // ---- per-lane affine over 8 channels (c8*8 .. c8*8+7) ----
  const int c8 = lane & 15;
  const int grp = lane >> 4;
  float scl8[8], sh8[8];
  #pragma unroll
  for (int j = 0; j < 8; j++) { scl8[j] = 1.0f; sh8[j] = 0.0f; }
  if (instats) {
    #pragma unroll
    for (int j = 0; j < 8; j++) {
      int c = c8 * 8 + j;
      float mu = instats[c] * (1.0f / NNODES);
      float var = instats[HID + c] * (1.0f / NNODES) - mu * mu;
      float s = gam[c] * rsqrtf(var + BN_EPS);
      scl8[j] = s;
      sh8[j] = bet[c] - mu * s;
    }
  }
  __syncthreads();  // sheL ready

  // ---- phase 1: gather (bf16 rows, 16B/lane, 4 edges per wave instr) ----
  {
    const short8* in8 = (const short8*)in_bf;  // row = 16 short8s
    int node0 = base + wave * 4;
    int degs[4];
    #pragma unroll
    for (int i = 0; i < 4; i++) {  // 4 independent loads in flight
      int nd = node0 + i;
      degs[i] = (nd < NNODES) ? min(cnt[nd], CAP) : 0;
    }
    for (int i = 0; i < 4; i++) {
      int node = node0 + i;
      int nrow = wave * 4 + i;
      float acc[8];
      #pragma unroll
      for (int j = 0; j < 8; j++) acc[j] = 0.0f;
      if (node < NNODES) {
        int deg = degs[i];
        const int* ep = eout + ((size_t)node << 6);
        if (grp == 0) {
          short8 s = in8[node * 16 + c8];
          #pragma unroll
          for (int j = 0; j < 8; j++)
            acc[j] = fmaf(bf2f((unsigned short)s[j]), scl8[j], sh8[j]);
        }
        int e = 0;
        for (; e + 8 <= deg; e += 8) {  // 8 edges: 2 per slot
          int pA = ep[e + grp];
          int pB = ep[e + 4 + grp];
          short8 xA = in8[(pA & 0xFFFF) * 16 + c8];
          short8 xB = in8[(pB & 0xFFFF) * 16 + c8];
          const float4* sA = (const float4*)&sheL[((pA >> 16) << 7) + c8 * 8];
          const float4* sB = (const float4*)&sheL[((pB >> 16) << 7) + c8 * 8];
          float4 sA0 = sA[0], sA1 = sA[1], sB0 = sB[0], sB1 = sB[1];
          #pragma unroll
          for (int j = 0; j < 8; j++) {
            float seA = (j < 4) ? ((const float*)&sA0)[j] : ((const float*)&sA1)[j - 4];
            float seB = (j < 4) ? ((const float*)&sB0)[j] : ((const float*)&sB1)[j - 4];
            acc[j] += fmaxf(fmaf(bf2f((unsigned short)xA[j]), scl8[j], seA), 0.0f) +
                      fmaxf(fmaf(bf2f((unsigned short)xB[j]), scl8[j], seB), 0.0f);
          }
        }
        if (e + 4 <= deg) {
          int pA = ep[e + grp];
          short8 xA = in8[(pA & 0xFFFF) * 16 + c8];
          const float4* sA = (const float4*)&sheL[((pA >> 16) << 7) + c8 * 8];
          float4 sA0 = sA[0], sA1 = sA[1];
          #pragma unroll
          for (int j = 0; j < 8; j++) {
            float seA = (j < 4) ? ((const float*)&sA0)[j] : ((const float*)&sA1)[j - 4];
            acc[j] += fmaxf(fmaf(bf2f((unsigned short)xA[j]), scl8[j], seA), 0.0f);
          }
          e += 4;
        }
        int rem = deg - e;  // 0..3
        if (grp < rem) {
          int pA = ep[e + grp];
          short8 xA = in8[(pA & 0xFFFF) * 16 + c8];
          const float4* sA = (const float4*)&sheL[((pA >> 16) << 7) + c8 * 8];
          float4 sA0 = sA[0], sA1 = sA[1];
          #pragma unroll
          for (int j = 0; j < 8; j++) {
            float seA = (j < 4) ? ((const float*)&sA0)[j] : ((const float*)&sA1)[j - 4];
            acc[j] += fmaxf(fmaf(bf2f((unsigned short)xA[j]), scl8[j], seA), 0.0f);
          }
        }
      }
      // combine the 4 edge-slot partials (same channels across slots)
      #pragma unroll
      for (int j = 0; j < 8; j++) {
        acc[j] += __shfl_xor(acc[j], 16);
        acc[j] += __shfl_xor(acc[j], 32);
      }
      if (grp == 0) {
        float4 lo = make_float4(acc[0], acc[1], acc[2], acc[3]);
        float4 hi = make_float4(acc[4], acc[5], acc[6], acc[7]);
        *(float4*)&hA[nrow * LDAF + c8 * 8] = lo;
        *(float4*)&hA[nrow * LDAF + c8 * 8 + 4] = hi;
      }
    }
  }
  __syncthreads();

  const int col = lane & 15;
  const int quad = lane >> 4;
  const int rbase = quad * 4;
  const int ch0 = wave * 16 + col;  // this wave's 16-channel tile
  const int aoff = quad * 8;

  // ---- phase 2: GEMM1 (hA @ W1 + b1, relu) -> back into hA ----
  {
    f32x4 a0 = {0.f, 0.f, 0.f, 0.f}, a1 = a0;
    #pragma unroll
    for (int q = 0; q < 4; q++) {
      int f0 = wave * 256 + q * 64 + lane;
      short8 b0h = Wh[f0], b0l = Wl[f0];
      short8 a0h, a0l, a1h, a1l;
      split8(&hA[col * LDAF + q * 32 + aoff], a0h, a0l);
      split8(&hA[(16 + col) * LDAF + q * 32 + aoff], a1h, a1l);
      a0 = __builtin_amdgcn_mfma_f32_16x16x32_bf16(a0h, b0h, a0, 0, 0, 0);
      a0 = __builtin_amdgcn_mfma_f32_16x16x32_bf16(a0l, b0h, a0, 0, 0, 0);
      a0 = __builtin_amdgcn_mfma_f32_16x16x32_bf16(a0h, b0l, a0, 0, 0, 0);
      a1 = __builtin_amdgcn_mfma_f32_16x16x32_bf16(a1h, b0h, a1, 0, 0, 0);
      a1 = __builtin_amdgcn_mfma_f32_16x16x32_bf16(a1l, b0h, a1, 0, 0, 0);
      a1 = __builtin_amdgcn_mfma_f32_16x16x32_bf16(a1h, b0l, a1, 0, 0, 0);
    }
    __syncthreads();  // all GEMM1 reads of hA complete
    float bb0 = b1[ch0];
    #pragma unroll
    for (int r = 0; r < 4; r++) {
      hA[(rbase + r) * LDAF + ch0] = fmaxf(a0[r] + bb0, 0.0f);
      hA[(16 + rbase + r) * LDAF + ch0] = fmaxf(a1[r] + bb0, 0.0f);
    }
  }
  __syncthreads();

  // ---- phase 3: GEMM2 (h1 @ W2 + b2, relu) -> back into hA ----
  {
    f32x4 a0 = {0.f, 0.f, 0.f, 0.f}, a1 = a0;
    #pragma unroll
    for (int q = 0; q < 4; q++) {
      int f0 = 2048 + wave * 256 + q * 64 + lane;  // gemm2 frags
      short8 b0h = Wh[f0], b0l = Wl[f0];
      short8 a0h, a0l, a1h, a1l;
      split8(&hA[col * LDAF + q * 32 + aoff], a0h, a0l);
      split8(&hA[(16 + col) * LDAF + q * 32 + aoff], a1h, a1l);
      a0 = __builtin_amdgcn_mfma_f32_16x16x32_bf16(a0h, b0h, a0, 0, 0, 0);
      a0 = __builtin_amdgcn_mfma_f32_16x16x32_bf16(a0l, b0h, a0, 0, 0, 0);
      a0 = __builtin_amdgcn_mfma_f32_16x16x32_bf16(a0h, b0l, a0, 0, 0, 0);
      a1 = __builtin_amdgcn_mfma_f32_16x16x32_bf16(a1h, b0h, a1, 0, 0, 0);
      a1 = __builtin_amdgcn_mfma_f32_16x16x32_bf16(a1l, b0h, a1, 0, 0, 0);
      a1 = __builtin_amdgcn_mfma_f32_16x16x32_bf16(a1h, b0l, a1, 0, 0, 0);
    }
    __syncthreads();  // all GEMM2 reads complete
    float bb0 = b2[ch0];
    #pragma unroll
    for (int r = 0; r < 4; r++) {
      hA[(rbase + r) * LDAF + ch0] = fmaxf(a0[r] + bb0, 0.0f);
      hA[(16 + rbase + r) * LDAF + ch0] = fmaxf(a1[r] + bb0, 0.0f);
    }
  }
  __syncthreads();

  // ---- phase 4: epilogue (h2 in hA); first 256 threads only ----
  if (tid < 256) {
    const int c = tid & 127;
    const int yy = tid >> 7;
    float lsum = 0.0f, lsq = 0.0f;
    if (out_bf) {
      #pragma unroll 4
      for (int i = 0; i < 16; i++) {
        int n = yy * 16 + i;
        int node = base + n;
        if (node < NNODES) {
          float v = hA[n * LDAF + c];
          out_bf[node * HID + c] = f2bf(v);
          lsum += v;
          lsq += v * v;
        }
      }
    } else {
      int curg = -1;
      float pacc = 0.0f;
      for (int i = 0; i < 16; i++) {
        int n = yy * 16 + i;
        int node = base + n;
        if (node < NNODES) {
          float v = hA[n * LDAF + c];
          lsum += v;
          lsq += v * v;
          int bg = batch[node];
          if (bg != curg) {
            if (curg >= 0) unsafeAtomicAdd(&gpool[curg * HID + c], pacc);
            curg = bg;
            pacc = 0.0f;
          }
          pacc += v;
        }
      }
      if (curg >= 0) unsafeAtomicAdd(&gpool[curg * HID + c], pacc);
    }
    unsafeAtomicAdd(&stats[c], lsum);
    unsafeAtomicAdd(&stats[HID + c], lsq);
  }
}

// ---------------------------------------------------------------------------
// out[g,c] = scl_c * gpool[g,c] + cnt_g * sh_c  (BN affine commutes with pool)
__device__ __forceinline__ int lbound(const int* __restrict__ arr, int n,
                                      int key) {
  int lo = 0, hi = n;
  while (lo < hi) {
    int mid = (lo + hi) >> 1;
    if (arr[mid] < key) lo = mid + 1; else hi = mid;
  }
  return lo;
}

__global__ __launch_bounds__(128) void finish_kernel(
    const float* __restrict__ gpool, const float* __restrict__ stats,
    const float* __restrict__ gam, const float* __restrict__ bet,
    const int* __restrict__ batch, float* __restrict__ out) {
  __shared__ int cnt_s;
  int g = blockIdx.x, c = threadIdx.x;
  if (c == 0)
    cnt_s = lbound(batch, NNODES, g + 1) - lbound(batch, NNODES, g);
  __syncthreads();
  float mu = stats[c] * (1.0f / NNODES);
  float var = stats[HID + c] * (1.0f / NNODES) - mu * mu;
  float scl = gam[c] * rsqrtf(var + BN_EPS);
  float sh = bet[c] - mu * scl;
  out[g * HID + c] = fmaf(gpool[g * HID + c], scl, (float)cnt_s * sh);
}

// ---------------------------------------------------------------------------
extern "C" void kernel_launch(void* const* d_in, const int* in_sizes, int n_in,
                              void* d_out, int out_size, void* d_ws, size_t ws_size,
                              hipStream_t stream) {
  const int* x_idx = (const int*)d_in[0];
  const int* eidx = (const int*)d_in[1];   // [2, E]: src row then dst row
  const int* eattr = (const int*)d_in[2];
  const int* batch = (const int*)d_in[3];
  const float* node_emb = (const float*)d_in[4];
  const float* edge_emb = (const float*)d_in[5];
  const float* W1 = (const float*)d_in[6];
  const float* b1 = (const float*)d_in[7];
  const float* W2 = (const float*)d_in[8];
  const float* b2 = (const float*)d_in[9];
  const float* bn_g = (const float*)d_in[10];
  const float* bn_b = (const float*)d_in[11];
  float* out = (float*)d_out;

  const size_t nfeat = (size_t)NNODES * HID;
  unsigned short* xbf = (unsigned short*)d_ws;  // [N,H] bf16
  unsigned short* h2bf = xbf + nfeat;           // [N,H] bf16
  float* stats0 = (float*)(h2bf + nfeat);       // [2,H]
  float* stats1 = stats0 + 2 * HID;             // [2,H]
  float* gpool = stats1 + 2 * HID;              // [G,H]
  int* cnt = (int*)(gpool + NGRAPHS * HID);     // [N]   (zeroed with stats)
  int* eout = cnt + NNODES;                     // [N*CAP]
  unsigned short* Wpk = (unsigned short*)(eout + (size_t)NNODES * CAP);
  size_t needed = (size_t)((char*)(Wpk + 131072) - (char*)d_ws);
  if (ws_size < needed) return;  // fails validation loudly, doesn't corrupt

  // zero stats0, stats1, gpool, cnt in one shot (contiguous)
  hipMemsetAsync(stats0, 0, (4 * HID + NGRAPHS * HID + NNODES) * sizeof(int),
                 stream);

  prep_kernel<<<1024, 256, 0, stream>>>(x_idx, node_emb, (unsigned int*)xbf,
                                        eidx, eattr, cnt, eout, W1, W2, Wpk);

  const short8* Wfh = (const short8*)Wpk;  // 8192 frags (hi)
  const short8* Wfl = Wfh + 8192;          // 8192 frags (lo)
  // layer 0: in = xbf (identity affine), out -> h2bf, stats0
  gine_mlp_kernel<<<GRID_GINE, 512, 0, stream>>>(
      xbf, nullptr, nullptr, nullptr, cnt, eout, edge_emb,
      Wfh + 0 * 2048, Wfl + 0 * 2048, b1, b2, h2bf, stats0, nullptr, nullptr);
  // layer 1: in = h2bf with BN(layer0) folded, out -> gpool + stats1
  gine_mlp_kernel<<<GRID_GINE, 512, 0, stream>>>(
      h2bf, stats0, bn_g, bn_b, cnt, eout, edge_emb,
      Wfh + 2 * 2048, Wfl + 2 * 2048, b1 + HID, b2 + HID, nullptr, stats1,
      batch, gpool);
  // final: out = scl*gpool + cnt*sh
  finish_kernel<<<NGRAPHS, 128, 0, stream>>>(gpool, stats1, bn_g + HID,
                                             bn_b + HID, batch, out);
}